// Round 2
// baseline (221.083 us; speedup 1.0000x reference)
//
#include <hip/hip_runtime.h>

#define NTOT 8192
#define NROW 2048
#define NU 4096
#define D 64
#define MAXN 64
#define ND (NTOT*D)

__device__ __forceinline__ float wsum(float x){
  #pragma unroll
  for(int o=32;o;o>>=1) x += __shfl_xor(x,o);
  return x;
}
__device__ __forceinline__ float wmax(float x){
  #pragma unroll
  for(int o=32;o;o>>=1) x = fmaxf(x,__shfl_xor(x,o));
  return x;
}
__device__ __forceinline__ float bcastf(float x, int k){
  return __uint_as_float(__builtin_amdgcn_readlane(__float_as_uint(x), (unsigned)k));
}
__device__ __forceinline__ int bcasti(int x, int k){
  return (int)__builtin_amdgcn_readlane((unsigned)x, (unsigned)k);
}

// ---- shared attention row routine: softmax(e*adj) @ h, analytic dense form ----
__device__ __forceinline__ float gat_attn_row(const float* __restrict__ h,
    const float* __restrict__ kvv, const float* __restrict__ S,
    const int* __restrict__ cols, int cnt, float q, float ab, int lane){
  int t = lane;
  int col = (t < cnt) ? cols[t] : 0;
  float e = -1e30f;
  if(t < cnt){
    float xx = q + kvv[col] + ab;
    e = (xx >= 0.f) ? xx : 0.01f * xx;
  }
  float m  = fmaxf(0.f, wmax(e));           // non-edges contribute e=0
  float w  = (t < cnt) ? expf(e - m) : 0.f;
  float em = expf(-m);
  float Z  = (float)(NTOT - cnt) * em + wsum(w);
  float acc = 0.f, hsum = 0.f;
  for(int tt = 0; tt < cnt; ++tt){
    float wt = bcastf(w, tt);
    int   jc = bcasti(col, tt);
    float hv = h[jc*D + lane];
    acc  = fmaf(wt, hv, acc);
    hsum += hv;
  }
  float outv = (acc + em * (S[lane] - hsum)) / Z;
  return fmaxf(outv, 0.f);
}

// ---- Kernel A: build ELL (blocks 0..2047) | concat emb (2048..4095) | init (4096) ----
__global__ __launch_bounds__(256) void kA(const float* __restrict__ adj,
    const float* __restrict__ ut, const float* __restrict__ it,
    float* __restrict__ all_emb, int* __restrict__ ell, int* __restrict__ nnz,
    float* __restrict__ Svec0, float* __restrict__ Svec1, float* __restrict__ gcn1){
  int bid = blockIdx.x, tid = threadIdx.x;
  if(bid < NROW){
    int lane = tid & 63;
    int row  = bid*4 + (tid >> 6);
    ell[row*MAXN + lane] = NTOT;                    // sentinel init (64 slots)
    const float4* arow = (const float4*)(adj + (size_t)row * NTOT);
    int base = 0;
    for(int c0 = 0; c0 < NTOT/4; c0 += 64){
      float4 v = arow[c0 + lane];
      int nib = (v.x!=0.f?1:0) | (v.y!=0.f?2:0) | (v.z!=0.f?4:0) | (v.w!=0.f?8:0);
      if(__ballot(nib != 0) == 0ull) continue;      // skip empty 256-col chunk
      #pragma unroll
      for(int j = 0; j < 4; ++j){
        unsigned long long m = __ballot(((nib>>j)&1) != 0);
        if(m){
          if((nib>>j)&1){
            int below = __builtin_amdgcn_mbcnt_hi((unsigned)(m>>32),
                        __builtin_amdgcn_mbcnt_lo((unsigned)m, 0u));
            int slot = base + below;
            if(slot < MAXN) ell[row*MAXN + slot] = (c0 + lane)*4 + j;
          }
          base += __popcll(m);
        }
      }
    }
    if(lane == 0) nnz[row] = base > MAXN ? MAXN : base;
  } else if(bid < 2*NROW){
    int i = (bid - NROW)*256 + tid;
    all_emb[i] = (i < NU*D) ? ut[i] : it[i - NU*D];
  } else {
    if(tid < D){
      Svec0[tid] = 0.f; Svec1[tid] = 0.f;
      all_emb[ND + tid] = 0.f;                      // sentinel zero row
      gcn1[ND + tid]    = 0.f;
    }
  }
}

// ---- Kernel B: gcn1 (blocks 0..2047) | gat_h0 + Svec0 partial (2048..4095) ----
__global__ __launch_bounds__(256) void kB(const float* __restrict__ all_emb,
    const int* __restrict__ ell, const int* __restrict__ nnz,
    const float* __restrict__ gcn_W, const float* __restrict__ gcn_b,
    const float* __restrict__ gat_W, const float* __restrict__ gat_b,
    const float* __restrict__ attn_W,
    float* __restrict__ gcn1, float* __restrict__ h0,
    float* __restrict__ qv0, float* __restrict__ kv0, float* __restrict__ Svec0){
  __shared__ float Ws[D*D];
  __shared__ float red[4][D];
  int tid = threadIdx.x, lane = tid & 63, wid = tid >> 6;
  int bid = blockIdx.x;
  if(bid < NROW){
    for(int i = tid; i < D*D; i += 256) Ws[i] = gcn_W[i];
    __syncthreads();
    int row = bid*4 + wid;
    int cnt = nnz[row];
    const int* cols = ell + row*MAXN;
    float acc = 0.f;
    int cnt8 = (cnt + 7) & ~7;
    for(int t = 0; t < cnt8; t += 8){
      #pragma unroll
      for(int u = 0; u < 8; ++u){
        int j = cols[t + u];                        // sentinel -> zero row
        acc += all_emb[j*D + lane];
      }
    }
    float y = gcn_b[lane];
    #pragma unroll 16
    for(int k = 0; k < D; ++k) y = fmaf(bcastf(acc, k), Ws[k*D + lane], y);
    gcn1[row*D + lane] = fmaxf(y, 0.f);
  } else {
    for(int i = tid; i < D*D; i += 256) Ws[i] = gat_W[i];
    __syncthreads();
    int row = (bid - NROW)*4 + wid;
    float xr = all_emb[row*D + lane];
    float h = gat_b[lane];
    #pragma unroll 16
    for(int k = 0; k < D; ++k) h = fmaf(bcastf(xr, k), Ws[k*D + lane], h);
    h0[row*D + lane] = h;
    float q  = wsum(h * attn_W[lane]);
    float kk = wsum(h * attn_W[D + lane]);
    if(lane == 0){ qv0[row] = q; kv0[row] = kk; }
    red[wid][lane] = h;
    __syncthreads();
    if(wid == 0){
      float s = red[0][lane] + red[1][lane] + red[2][lane] + red[3][lane];
      atomicAdd(&Svec0[lane], s);
    }
  }
}

// ---- Kernel C: gcn2 (blocks 0..2047) | attn0 + fuse0 + gat_h1 + Svec1 (2048..4095) ----
__global__ __launch_bounds__(256) void kC(
    const float* __restrict__ all_emb, const int* __restrict__ ell, const int* __restrict__ nnz,
    const float* __restrict__ gcn1, const float* __restrict__ h0,
    const float* __restrict__ qv0, const float* __restrict__ kv0, const float* __restrict__ Svec0,
    const float* __restrict__ gcn_W, const float* __restrict__ gcn_b,
    const float* __restrict__ gat_W, const float* __restrict__ gat_b,
    const float* __restrict__ attn_W, const float* __restrict__ attn_b,
    const float* __restrict__ fuse_W, const float* __restrict__ fuse_b,
    const float* __restrict__ layer_w,
    float* __restrict__ gcn2, float* __restrict__ h1,
    float* __restrict__ qv1, float* __restrict__ kv1, float* __restrict__ Svec1,
    float* __restrict__ fusedb){
  __shared__ float Ws[D*D];
  __shared__ float red[4][D];
  int tid = threadIdx.x, lane = tid & 63, wid = tid >> 6;
  int bid = blockIdx.x;
  if(bid < NROW){
    for(int i = tid; i < D*D; i += 256) Ws[i] = gcn_W[D*D + i];
    __syncthreads();
    int row = bid*4 + wid;
    int cnt = nnz[row];
    const int* cols = ell + row*MAXN;
    float acc = 0.f;
    int cnt8 = (cnt + 7) & ~7;
    for(int t = 0; t < cnt8; t += 8){
      #pragma unroll
      for(int u = 0; u < 8; ++u){
        int j = cols[t + u];
        acc += gcn1[j*D + lane];
      }
    }
    float y = gcn_b[D + lane];
    #pragma unroll 16
    for(int k = 0; k < D; ++k) y = fmaf(bcastf(acc, k), Ws[k*D + lane], y);
    gcn2[row*D + lane] = fmaxf(y, 0.f);
  } else {
    int row = (bid - NROW)*4 + wid;
    int cnt = nnz[row];
    const int* cols = ell + row*MAXN;
    float g1 = gat_attn_row(h0, kv0, Svec0, cols, cnt, qv0[row], attn_b[0], lane);
    float gc1 = gcn1[row*D + lane];
    float l0 = layer_w[0], l1 = layer_w[1];
    float mx = fmaxf(l0, l1);
    float e0 = expf(l0 - mx), e1 = expf(l1 - mx);
    float lw0 = e0 / (e0 + e1);
    // fuse layer-0: y = [gcn1, gat1] @ F0 + b0  (staged in two 16K halves)
    for(int i = tid; i < D*D; i += 256) Ws[i] = fuse_W[i];
    __syncthreads();
    float y = fuse_b[lane];
    #pragma unroll 16
    for(int k = 0; k < D; ++k) y = fmaf(bcastf(gc1, k), Ws[k*D + lane], y);
    __syncthreads();
    for(int i = tid; i < D*D; i += 256) Ws[i] = fuse_W[D*D + i];
    __syncthreads();
    #pragma unroll 16
    for(int k = 0; k < D; ++k) y = fmaf(bcastf(g1, k), Ws[k*D + lane], y);
    fusedb[row*D + lane] = lw0 * fmaxf(y, 0.f);
    __syncthreads();
    // h1 = gat1 @ gat_W[1] + gat_b[1]
    for(int i = tid; i < D*D; i += 256) Ws[i] = gat_W[D*D + i];
    __syncthreads();
    float h = gat_b[D + lane];
    #pragma unroll 16
    for(int k = 0; k < D; ++k) h = fmaf(bcastf(g1, k), Ws[k*D + lane], h);
    h1[row*D + lane] = h;
    float qq = wsum(h * attn_W[2*D + lane]);
    float kk = wsum(h * attn_W[3*D + lane]);
    if(lane == 0){ qv1[row] = qq; kv1[row] = kk; }
    red[wid][lane] = h;
    __syncthreads();
    if(wid == 0){
      float s = red[0][lane] + red[1][lane] + red[2][lane] + red[3][lane];
      atomicAdd(&Svec1[lane], s);
    }
  }
}

// ---- Kernel E: attn1 + fuse1 (2048 blocks) ----
__global__ __launch_bounds__(256) void kE(
    const int* __restrict__ ell, const int* __restrict__ nnz,
    const float* __restrict__ gcn2, const float* __restrict__ h1,
    const float* __restrict__ qv1, const float* __restrict__ kv1, const float* __restrict__ Svec1,
    const float* __restrict__ attn_b,
    const float* __restrict__ fuse_W, const float* __restrict__ fuse_b,
    const float* __restrict__ layer_w,
    float* __restrict__ fusedb){
  __shared__ float Ws[D*D];
  int tid = threadIdx.x, lane = tid & 63, wid = tid >> 6;
  int row = blockIdx.x*4 + wid;
  int cnt = nnz[row];
  const int* cols = ell + row*MAXN;
  float g2 = gat_attn_row(h1, kv1, Svec1, cols, cnt, qv1[row], attn_b[1], lane);
  float gc2 = gcn2[row*D + lane];
  float l0 = layer_w[0], l1 = layer_w[1];
  float mx = fmaxf(l0, l1);
  float e0 = expf(l0 - mx), e1 = expf(l1 - mx);
  float lw1 = e1 / (e0 + e1);
  for(int i = tid; i < D*D; i += 256) Ws[i] = fuse_W[2*D*D + i];
  __syncthreads();
  float y = fuse_b[D + lane];
  #pragma unroll 16
  for(int k = 0; k < D; ++k) y = fmaf(bcastf(gc2, k), Ws[k*D + lane], y);
  __syncthreads();
  for(int i = tid; i < D*D; i += 256) Ws[i] = fuse_W[3*D*D + i];
  __syncthreads();
  #pragma unroll 16
  for(int k = 0; k < D; ++k) y = fmaf(bcastf(g2, k), Ws[k*D + lane], y);
  fusedb[row*D + lane] += lw1 * fmaxf(y, 0.f);
}

// ---- Kernel F: scoring + critic (1024 blocks) ----
__global__ __launch_bounds__(256) void kF(const float* __restrict__ fused,
    const int* __restrict__ users, const int* __restrict__ pos, const int* __restrict__ neg,
    const float* __restrict__ AW, const float* __restrict__ abias,
    const float* __restrict__ cW1, const float* __restrict__ cb1,
    const float* __restrict__ cW2, const float* __restrict__ cb2,
    float* __restrict__ out){
  __shared__ float AWs[D*D];
  __shared__ float C1s[2*D*D];
  __shared__ float abs_[D], cb1s[D], C2s[D];
  int tid = threadIdx.x;
  for(int i = tid; i < D*D; i += 256) AWs[i] = AW[i];
  for(int i = tid; i < 2*D*D; i += 256) C1s[i] = cW1[i];
  if(tid < D){
    abs_[tid] = abias[tid];
    cb1s[tid] = cb1[tid];
    C2s[tid]  = cW2[tid];
  }
  __syncthreads();
  int lane = tid & 63;
  int bi   = blockIdx.x*4 + (tid >> 6);
  int ui = users[bi], pi = pos[bi] + NU, ni = neg[bi] + NU;
  float ud = fused[ui*D + lane], pd = fused[pi*D + lane], nd = fused[ni*D + lane];
  float ufd = abs_[lane];
  #pragma unroll 16
  for(int k = 0; k < D; ++k) ufd = fmaf(bcastf(ud, k), AWs[k*D + lane], ufd);
  float ps = wsum(ufd * pd);
  float ns = wsum(ufd * nd);
  float hu = cb1s[lane];
  #pragma unroll 16
  for(int k = 0; k < D; ++k) hu = fmaf(bcastf(ud, k), C1s[k*D + lane], hu);
  float hp = hu, hn = hu;
  #pragma unroll 16
  for(int k = 0; k < D; ++k){
    float pk = bcastf(pd, k), nk = bcastf(nd, k);
    hp = fmaf(pk, C1s[(D+k)*D + lane], hp);
    hn = fmaf(nk, C1s[(D+k)*D + lane], hn);
  }
  hp = fmaxf(hp, 0.f); hn = fmaxf(hn, 0.f);
  float cp = wsum(hp * C2s[lane]);
  float cn = wsum(hn * C2s[lane]);
  if(lane == 0){
    out[bi]         = ps;
    out[4096  + bi] = ns;
    out[8192  + bi] = cp + cb2[0];
    out[12288 + bi] = cn + cb2[0];
  }
}

extern "C" void kernel_launch(void* const* d_in, const int* in_sizes, int n_in,
                              void* d_out, int out_size, void* d_ws, size_t ws_size,
                              hipStream_t stream){
  const float* adj        = (const float*)d_in[0];
  const int*   users      = (const int*)d_in[1];
  const int*   pos        = (const int*)d_in[2];
  const int*   neg        = (const int*)d_in[3];
  const float* user_table = (const float*)d_in[4];
  const float* item_table = (const float*)d_in[5];
  const float* gcn_W      = (const float*)d_in[6];
  const float* gcn_b      = (const float*)d_in[7];
  const float* gat_W      = (const float*)d_in[8];
  const float* gat_b      = (const float*)d_in[9];
  const float* attn_W     = (const float*)d_in[10];
  const float* attn_b     = (const float*)d_in[11];
  const float* fuse_W     = (const float*)d_in[12];
  const float* fuse_b     = (const float*)d_in[13];
  const float* actor_W    = (const float*)d_in[14];
  const float* actor_b    = (const float*)d_in[15];
  const float* cW1        = (const float*)d_in[16];
  const float* cb1        = (const float*)d_in[17];
  const float* cW2        = (const float*)d_in[18];
  const float* cb2        = (const float*)d_in[19];
  const float* layer_w    = (const float*)d_in[20];

  float* ws      = (float*)d_ws;
  float* all_emb = ws;                   // ND + D (zero row)
  float* gcn1    = all_emb + ND + D;     // ND + D (zero row)
  float* gcn2    = gcn1 + ND + D;        // ND
  float* h0      = gcn2 + ND;            // ND
  float* h1      = h0 + ND;              // ND
  float* fusedb  = h1 + ND;              // ND
  float* qv0     = fusedb + ND;          // NTOT
  float* kv0     = qv0 + NTOT;
  float* qv1     = kv0 + NTOT;
  float* kv1     = qv1 + NTOT;
  float* Svec0   = kv1 + NTOT;           // D
  float* Svec1   = Svec0 + D;            // D
  int*   nnz     = (int*)(Svec1 + D);    // NTOT
  int*   ell     = nnz + NTOT;           // NTOT*MAXN

  kA<<<2*NROW + 1, 256, 0, stream>>>(adj, user_table, item_table,
                                     all_emb, ell, nnz, Svec0, Svec1, gcn1);
  kB<<<2*NROW, 256, 0, stream>>>(all_emb, ell, nnz, gcn_W, gcn_b, gat_W, gat_b,
                                 attn_W, gcn1, h0, qv0, kv0, Svec0);
  kC<<<2*NROW, 256, 0, stream>>>(all_emb, ell, nnz, gcn1, h0, qv0, kv0, Svec0,
                                 gcn_W, gcn_b, gat_W, gat_b, attn_W, attn_b,
                                 fuse_W, fuse_b, layer_w,
                                 gcn2, h1, qv1, kv1, Svec1, fusedb);
  kE<<<NROW, 256, 0, stream>>>(ell, nnz, gcn2, h1, qv1, kv1, Svec1, attn_b,
                               fuse_W, fuse_b, layer_w, fusedb);
  kF<<<1024, 256, 0, stream>>>(fusedb, users, pos, neg, actor_W, actor_b,
                               cW1, cb1, cW2, cb2, (float*)d_out);
}